// Round 2
// baseline (1406.818 us; speedup 1.0000x reference)
//
#include <hip/hip_runtime.h>
#include <hip/hip_bf16.h>
#include <cstdint>
#include <cstddef>

#define FDIM 128
#define LOG2_F 0.69314718055994530942f

__device__ __forceinline__ float ssp_f(float x) {
    // softplus(x) - log(2), numerically stable
    return fmaxf(x, 0.0f) + log1pf(__expf(-fabsf(x))) - LOG2_F;
}

// out[M,128] = maybe_ssp( maybe_ssp(A)[M,128] @ W^T[128,128] + b ) (+ addsrc | + x*u)
// ADDMODE: 0 = none, 1 = += addsrc, 2 = += x*u
template<int ACT_IN, int ACT_OUT, int ADDMODE>
__global__ __launch_bounds__(256, 2) void gemm_node(
    const float* __restrict__ A, const float* __restrict__ W,
    const float* __restrict__ bias, const float* __restrict__ addsrc,
    const float* __restrict__ xin, const float* __restrict__ u,
    float* __restrict__ outf, int M)
{
    __shared__ float Wt[64][132];   // Wt[kk][f] = W[f][half*64+kk]   (k-major, conflict-free reads)
    __shared__ float As[32][132];   // A tile, 32 rows

    const int tid = threadIdx.x;
    const int row0 = blockIdx.x * 32;

    // load A tile (coalesced), apply input activation
    for (int i = tid; i < 32 * FDIM; i += 256) {
        int r = i >> 7, k = i & 127;
        int gr = row0 + r;
        float v = (gr < M) ? A[(size_t)gr * FDIM + k] : 0.0f;
        if (ACT_IN) v = ssp_f(v);
        As[r][k] = v;
    }

    const int cg = tid & 31;   // col group: cols 4*cg .. 4*cg+3
    const int rg = tid >> 5;   // row group: rows 4*rg .. 4*rg+3
    const int cg4 = cg * 4;

    float acc[4][4] = {};

    for (int half = 0; half < 2; half++) {
        __syncthreads();   // As ready (1st pass) / all Wt reads done (2nd pass)
        // load W half, transposed into LDS (global reads coalesced)
        for (int i = tid; i < 64 * FDIM; i += 256) {
            int f = i >> 6, kk = i & 63;
            Wt[kk][f] = W[f * FDIM + half * 64 + kk];
        }
        __syncthreads();

        const int kb = half * 64;
        #pragma unroll 2
        for (int k4 = 0; k4 < 64; k4 += 4) {
            float a[4][4], w[4][4];
            #pragma unroll
            for (int i = 0; i < 4; i++)
                *(float4*)a[i] = *(const float4*)&As[rg * 4 + i][kb + k4];
            #pragma unroll
            for (int q = 0; q < 4; q++)
                *(float4*)w[q] = *(const float4*)&Wt[k4 + q][cg4];
            #pragma unroll
            for (int i = 0; i < 4; i++)
                #pragma unroll
                for (int j = 0; j < 4; j++)
                    #pragma unroll
                    for (int q = 0; q < 4; q++)
                        acc[i][j] = fmaf(a[i][q], w[q][j], acc[i][j]);
        }
    }

    float b4[4];
    *(float4*)b4 = *(const float4*)&bias[cg4];
    float u4[4];
    if constexpr (ADDMODE == 2) {
        *(float4*)u4 = *(const float4*)&u[cg4];
    }

    #pragma unroll
    for (int i = 0; i < 4; i++) {
        int gr = row0 + rg * 4 + i;
        if (gr < M) {
            float r[4];
            #pragma unroll
            for (int j = 0; j < 4; j++) {
                float v = acc[i][j] + b4[j];
                if (ACT_OUT) v = ssp_f(v);
                r[j] = v;
            }
            if constexpr (ADDMODE == 1) {
                float ad[4];
                *(float4*)ad = *(const float4*)&addsrc[(size_t)gr * FDIM + cg4];
                #pragma unroll
                for (int j = 0; j < 4; j++) r[j] += ad[j];
            }
            if constexpr (ADDMODE == 2) {
                float xv[4];
                *(float4*)xv = *(const float4*)&xin[(size_t)gr * FDIM + cg4];
                #pragma unroll
                for (int j = 0; j < 4; j++) r[j] += xv[j] * u4[j];
            }
            *(float4*)&outf[(size_t)gr * FDIM + cg4] = *(float4*)r;
        }
    }
}

// Per edge (one wave each): gate = edge_attr[e] @ G_w^T;  accum[dst] += H[src] * gate
__global__ __launch_bounds__(256, 2) void edge_kernel(
    const int* __restrict__ ei, const float* __restrict__ ea,
    const float* __restrict__ Gw, const float* __restrict__ H,
    float* __restrict__ accum, int E)
{
    __shared__ float G2[64][130];   // G2[k][f] = Gw[f][k]  (k-major; float2 reads per lane)

    const int tid = threadIdx.x;
    for (int i = tid; i < FDIM * 64; i += 256) {
        int f = i >> 6, k = i & 63;
        G2[k][f] = Gw[(size_t)f * 64 + k];
    }
    __syncthreads();

    const int lane = tid & 63;
    const int wv = tid >> 6;
    const int nw = gridDim.x * 4;

    for (int e = blockIdx.x * 4 + wv; e < E; e += nw) {
        int sn = ei[e];
        int dn = ei[E + e];
        float eav = ea[(size_t)e * 64 + lane];
        float g0 = 0.f, g1 = 0.f;
        #pragma unroll 8
        for (int k = 0; k < 64; k++) {
            float ek = __shfl(eav, k, 64);
            float2 g = *(const float2*)&G2[k][lane * 2];
            g0 = fmaf(ek, g.x, g0);
            g1 = fmaf(ek, g.y, g1);
        }
        float2 h = *(const float2*)&H[(size_t)sn * FDIM + lane * 2];
        float* dptr = &accum[(size_t)dn * FDIM + lane * 2];
        unsafeAtomicAdd(dptr, h.x * g0);
        unsafeAtomicAdd(dptr + 1, h.y * g1);
    }
}

extern "C" void kernel_launch(void* const* d_in, const int* in_sizes, int n_in,
                              void* d_out, int out_size, void* d_ws, size_t ws_size,
                              hipStream_t stream)
{
    const float* x      = (const float*)d_in[0];
    const int*   ei     = (const int*)d_in[1];
    const float* ea     = (const float*)d_in[2];
    const float* W_same = (const float*)d_in[3];
    const float* b_same = (const float*)d_in[4];
    const float* W_diff = (const float*)d_in[5];
    const float* b_diff = (const float*)d_in[6];
    const float* G_w    = (const float*)d_in[7];
    const float* rW1    = (const float*)d_in[8];
    const float* rb1    = (const float*)d_in[9];
    const float* rW2    = (const float*)d_in[10];
    const float* rb2    = (const float*)d_in[11];
    const float* W_last = (const float*)d_in[12];
    const float* b_last = (const float*)d_in[13];
    const float* u      = (const float*)d_in[14];

    const int N = in_sizes[0] / FDIM;
    const int E = in_sizes[1] / 2;
    const size_t NF = (size_t)N * FDIM;

    // outputs are FLOAT32 (reference output dtype): [out0 | msged_x], each N*F
    float* out0 = (float*)d_out;
    float* out1 = out0 + NF;        // msged_x, also the aggregation accumulator

    float* H  = (float*)d_ws;       // [N,F] message-source transform (dead after edge pass)
    float* yb = H;                  // alias: residual y buffer reuses H
    float* tb = H + NF;             // [N,F] residual state t

    const int gb = (N + 31) / 32;
    dim3 blk(256);

    // H = ssp(ssp(x) @ W_diff^T + b_diff)   [per-node precompute: E/N = 12x reuse]
    gemm_node<1,1,0><<<gb, blk, 0, stream>>>(x, W_diff, b_diff, nullptr, nullptr, nullptr, H, N);
    // out1 = ssp(ssp(x) @ W_same^T + b_same)   (fully written -> poison cleared)
    gemm_node<1,1,0><<<gb, blk, 0, stream>>>(x, W_same, b_same, nullptr, nullptr, nullptr, out1, N);
    // out1[dst] += H[src] * (edge_attr @ G_w^T)   -> out1 == msged_x (f32)
    edge_kernel<<<1024, blk, 0, stream>>>(ei, ea, G_w, H, out1, E);

    // residual stack: t = msged_x; for i: y = ssp(t)@W1^T+b1; t = t + (ssp(y)@W2^T+b2)
    gemm_node<1,0,0><<<gb, blk, 0, stream>>>(out1, rW1,          rb1,       nullptr, nullptr, nullptr, yb, N);
    gemm_node<1,0,1><<<gb, blk, 0, stream>>>(yb,   rW2,          rb2,       out1,    nullptr, nullptr, tb, N);
    gemm_node<1,0,0><<<gb, blk, 0, stream>>>(tb,   rW1 + 16384,  rb1 + 128, nullptr, nullptr, nullptr, yb, N);
    gemm_node<1,0,1><<<gb, blk, 0, stream>>>(yb,   rW2 + 16384,  rb2 + 128, tb,      nullptr, nullptr, tb, N);
    gemm_node<1,0,0><<<gb, blk, 0, stream>>>(tb,   rW1 + 32768,  rb1 + 256, nullptr, nullptr, nullptr, yb, N);
    gemm_node<1,0,1><<<gb, blk, 0, stream>>>(yb,   rW2 + 32768,  rb2 + 256, tb,      nullptr, nullptr, tb, N);

    // out0 = ssp(t) @ W_last^T + b_last + x*u   (f32)
    gemm_node<1,0,2><<<gb, blk, 0, stream>>>(tb, W_last, b_last, nullptr, x, u, out0, N);
}

// Round 4
// 911.591 us; speedup vs baseline: 1.5433x; 1.5433x over previous
//
#include <hip/hip_runtime.h>
#include <hip/hip_bf16.h>
#include <cstdint>
#include <cstddef>

#define FDIM 128
#define LOG2_F 0.69314718055994530942f

typedef __attribute__((ext_vector_type(8))) short bf16x8;
typedef __attribute__((ext_vector_type(4))) short short4v;
typedef __attribute__((ext_vector_type(4))) float f32x4;

__device__ __forceinline__ float ssp_f(float x) {
    // softplus(x) - log(2), numerically stable
    return fmaxf(x, 0.0f) + log1pf(__expf(-fabsf(x))) - LOG2_F;
}
__device__ __forceinline__ unsigned short f2b(float f) {
    uint32_t bits = __float_as_uint(f);
    bits += 0x7FFFu + ((bits >> 16) & 1u);
    return (unsigned short)(bits >> 16);
}
__device__ __forceinline__ float b2f(unsigned short h) {
    return __uint_as_float(((uint32_t)h) << 16);
}

// Convert all weight matrices to bf16 hi/lo planes in ws (once per launch).
// Layout in wb (shorts): mat m in [0,9): hi at m*32768, lo at m*32768+16384.
// m: 0=W_diff 1=W_same 2..4=rW1[i] 5..7=rW2[i] 8=W_last. Gw hi-only at 294912.
__global__ __launch_bounds__(256) void preconv_kernel(
    const float* __restrict__ Wdiff, const float* __restrict__ Wsame,
    const float* __restrict__ rW1, const float* __restrict__ rW2,
    const float* __restrict__ Wlast, const float* __restrict__ Gw,
    short* __restrict__ wb)
{
    int idx = blockIdx.x * 256 + threadIdx.x;
    const int NW = 9 * 16384;
    if (idx < NW) {
        int m = idx >> 14, off = idx & 16383;
        float v;
        if (m == 0) v = Wdiff[off];
        else if (m == 1) v = Wsame[off];
        else if (m < 5) v = rW1[(m - 2) * 16384 + off];
        else if (m < 8) v = rW2[(m - 5) * 16384 + off];
        else v = Wlast[off];
        unsigned short hi = f2b(v);
        unsigned short lo = f2b(v - b2f(hi));
        wb[m * 32768 + off] = (short)hi;
        wb[m * 32768 + 16384 + off] = (short)lo;
    } else if (idx < NW + 8192) {
        int off = idx - NW;
        wb[294912 + off] = (short)f2b(Gw[off]);
    }
}

// out[M,128] = maybe_ssp( maybe_ssp(A) @ W^T + b ) (+ addsrc | + x*u)
// MFMA 16x16x32 bf16 with split hi/lo (A and W): full ~f32 accuracy.
// Block: 64 rows x 128 cols, 4 waves in 2x2; wave tile 32x64.
template<int ACT_IN, int ACT_OUT, int ADDMODE>
__global__ __launch_bounds__(256, 3) void gemm_mfma(
    const float* __restrict__ A, const short* __restrict__ Whi,
    const short* __restrict__ Wlo, const float* __restrict__ bias,
    const float* __restrict__ addsrc, const float* __restrict__ xin,
    const float* __restrict__ u, float* __restrict__ outf, int M)
{
    __shared__ short Ahi[64][136];   // +8 pad: 2-way banks on b128 frag reads
    __shared__ short Alo[64][136];

    const int tid = threadIdx.x;
    const int row0 = blockIdx.x * 64;

    // stage A tile (coalesced float4), activation + hi/lo split
    for (int i = tid; i < 64 * 32; i += 256) {
        int r = i >> 5, c4 = (i & 31) * 4;
        int gr = row0 + r;
        float4 v;
        if (gr < M) v = *(const float4*)&A[(size_t)gr * FDIM + c4];
        else        v = make_float4(0.f, 0.f, 0.f, 0.f);
        if (ACT_IN) { v.x = ssp_f(v.x); v.y = ssp_f(v.y); v.z = ssp_f(v.z); v.w = ssp_f(v.w); }
        unsigned short h0 = f2b(v.x), h1 = f2b(v.y), h2 = f2b(v.z), h3 = f2b(v.w);
        short4v hv = { (short)h0, (short)h1, (short)h2, (short)h3 };
        short4v lv = { (short)f2b(v.x - b2f(h0)), (short)f2b(v.y - b2f(h1)),
                       (short)f2b(v.z - b2f(h2)), (short)f2b(v.w - b2f(h3)) };
        *(short4v*)&Ahi[r][c4] = hv;
        *(short4v*)&Alo[r][c4] = lv;
    }
    __syncthreads();

    const int lane = tid & 63;
    const int wid = tid >> 6;
    const int wm = wid & 1, wn = wid >> 1;   // 2x2 wave grid
    const int lr = lane & 15, lk = lane >> 4;

    f32x4 acc[2][4];
    #pragma unroll
    for (int mi = 0; mi < 2; mi++)
        #pragma unroll
        for (int ni = 0; ni < 4; ni++)
            acc[mi][ni] = 0;

    #pragma unroll
    for (int ks = 0; ks < 4; ks++) {
        const int k0 = ks * 32 + lk * 8;
        bf16x8 ah[2], al[2];
        #pragma unroll
        for (int mi = 0; mi < 2; mi++) {
            int row = wm * 32 + mi * 16 + lr;
            ah[mi] = *(const bf16x8*)&Ahi[row][k0];
            al[mi] = *(const bf16x8*)&Alo[row][k0];
        }
        #pragma unroll
        for (int ni = 0; ni < 4; ni++) {
            int col = wn * 64 + ni * 16 + lr;
            bf16x8 bh = *(const bf16x8*)&Whi[col * FDIM + k0];
            bf16x8 bl = *(const bf16x8*)&Wlo[col * FDIM + k0];
            #pragma unroll
            for (int mi = 0; mi < 2; mi++) {
                acc[mi][ni] = __builtin_amdgcn_mfma_f32_16x16x32_bf16(ah[mi], bh, acc[mi][ni], 0, 0, 0);
                acc[mi][ni] = __builtin_amdgcn_mfma_f32_16x16x32_bf16(al[mi], bh, acc[mi][ni], 0, 0, 0);
                acc[mi][ni] = __builtin_amdgcn_mfma_f32_16x16x32_bf16(ah[mi], bl, acc[mi][ni], 0, 0, 0);
            }
        }
    }

    // epilogue: C[row][col], col = lane&15 within tile, row = lk*4 + reg
    #pragma unroll
    for (int ni = 0; ni < 4; ni++) {
        int col = wn * 64 + ni * 16 + lr;
        float bv = bias[col];
        float uv = 0.f;
        if constexpr (ADDMODE == 2) uv = u[col];
        #pragma unroll
        for (int mi = 0; mi < 2; mi++) {
            #pragma unroll
            for (int r = 0; r < 4; r++) {
                int row = row0 + wm * 32 + mi * 16 + lk * 4 + r;
                if (row < M) {
                    float v = acc[mi][ni][r] + bv;
                    if (ACT_OUT) v = ssp_f(v);
                    if constexpr (ADDMODE == 1) v += addsrc[(size_t)row * FDIM + col];
                    if constexpr (ADDMODE == 2) v += xin[(size_t)row * FDIM + col] * uv;
                    outf[(size_t)row * FDIM + col] = v;
                }
            }
        }
    }
}

// Edge pass: gate[64e,128f] = ea @ Gw^T via MFMA (ea hi+lo, Gw hi),
// then accum[dst] += H[src] * gate with f32 atomics.
__global__ __launch_bounds__(256, 4) void edge_mfma(
    const int* __restrict__ ei, const float* __restrict__ ea,
    const short* __restrict__ GwB, const float* __restrict__ H,
    float* __restrict__ accum, int E)
{
    __shared__ short ehS[64][72];   // +8 pad
    __shared__ short elS[64][72];
    __shared__ int srcS[64], dstS[64];

    const int tid = threadIdx.x;
    const int e0 = blockIdx.x * 64;

    for (int i = tid; i < 64 * 16; i += 256) {
        int r = i >> 4, c4 = (i & 15) * 4;
        int ge = e0 + r;
        float4 v;
        if (ge < E) v = *(const float4*)&ea[(size_t)ge * 64 + c4];
        else        v = make_float4(0.f, 0.f, 0.f, 0.f);
        unsigned short h0 = f2b(v.x), h1 = f2b(v.y), h2 = f2b(v.z), h3 = f2b(v.w);
        short4v hv = { (short)h0, (short)h1, (short)h2, (short)h3 };
        short4v lv = { (short)f2b(v.x - b2f(h0)), (short)f2b(v.y - b2f(h1)),
                       (short)f2b(v.z - b2f(h2)), (short)f2b(v.w - b2f(h3)) };
        *(short4v*)&ehS[r][c4] = hv;
        *(short4v*)&elS[r][c4] = lv;
    }
    if (tid < 64) {
        int ge = e0 + tid;
        srcS[tid] = (ge < E) ? ei[ge] : 0;
        dstS[tid] = (ge < E) ? ei[E + ge] : 0;
    }
    __syncthreads();

    const int lane = tid & 63;
    const int w = tid >> 6;             // wave handles edges [w*16, w*16+16)
    const int lr = lane & 15, lk = lane >> 4;
    const int er = w * 16 + lr;

    bf16x8 ah0 = *(const bf16x8*)&ehS[er][lk * 8];
    bf16x8 ah1 = *(const bf16x8*)&ehS[er][32 + lk * 8];
    bf16x8 al0 = *(const bf16x8*)&elS[er][lk * 8];
    bf16x8 al1 = *(const bf16x8*)&elS[er][32 + lk * 8];

    f32x4 acc[8];
    #pragma unroll
    for (int t = 0; t < 8; t++) {
        const short* gp = &GwB[(t * 16 + lr) * 64 + lk * 8];
        bf16x8 b0 = *(const bf16x8*)gp;
        bf16x8 b1 = *(const bf16x8*)(gp + 32);
        f32x4 a = { 0.f, 0.f, 0.f, 0.f };
        a = __builtin_amdgcn_mfma_f32_16x16x32_bf16(ah0, b0, a, 0, 0, 0);
        a = __builtin_amdgcn_mfma_f32_16x16x32_bf16(al0, b0, a, 0, 0, 0);
        a = __builtin_amdgcn_mfma_f32_16x16x32_bf16(ah1, b1, a, 0, 0, 0);
        a = __builtin_amdgcn_mfma_f32_16x16x32_bf16(al1, b1, a, 0, 0, 0);
        acc[t] = a;
    }

    // scatter: lane's 4 edges are (w*16 + lk*4 + r), feature f = t*16 + lr
    #pragma unroll
    for (int r = 0; r < 4; r++) {
        int le = w * 16 + lk * 4 + r;
        if (e0 + le < E) {
            int s = srcS[le], d = dstS[le];
            const float* hp = &H[(size_t)s * FDIM + lr];
            float* ap = &accum[(size_t)d * FDIM + lr];
            #pragma unroll
            for (int t = 0; t < 8; t++) {
                unsafeAtomicAdd(&ap[t * 16], hp[t * 16] * acc[t][r]);
            }
        }
    }
}

extern "C" void kernel_launch(void* const* d_in, const int* in_sizes, int n_in,
                              void* d_out, int out_size, void* d_ws, size_t ws_size,
                              hipStream_t stream)
{
    const float* x      = (const float*)d_in[0];
    const int*   ei     = (const int*)d_in[1];
    const float* ea     = (const float*)d_in[2];
    const float* W_same = (const float*)d_in[3];
    const float* b_same = (const float*)d_in[4];
    const float* W_diff = (const float*)d_in[5];
    const float* b_diff = (const float*)d_in[6];
    const float* G_w    = (const float*)d_in[7];
    const float* rW1    = (const float*)d_in[8];
    const float* rb1    = (const float*)d_in[9];
    const float* rW2    = (const float*)d_in[10];
    const float* rb2    = (const float*)d_in[11];
    const float* W_last = (const float*)d_in[12];
    const float* b_last = (const float*)d_in[13];
    const float* u      = (const float*)d_in[14];

    const int N = in_sizes[0] / FDIM;
    const int E = in_sizes[1] / 2;
    const size_t NF = (size_t)N * FDIM;

    float* out0 = (float*)d_out;
    float* out1 = out0 + NF;            // msged_x + aggregation accumulator

    float* H  = (float*)d_ws;           // [N,F]; dead after edge pass
    float* yb = H;                      // alias for residual y
    float* tb = H + NF;                 // [N,F] residual state
    short* wb = (short*)(tb + NF);      // bf16 weight planes

    auto Whi = [&](int m) { return wb + m * 32768; };
    auto Wlo = [&](int m) { return wb + m * 32768 + 16384; };
    const short* GwB = wb + 294912;

    dim3 blk(256);
    const int gb = (N + 63) / 64;
    const int ge = (E + 63) / 64;

    preconv_kernel<<<(9 * 16384 + 8192 + 255) / 256, blk, 0, stream>>>(
        W_diff, W_same, rW1, rW2, W_last, G_w, wb);

    // H = ssp(ssp(x) @ W_diff^T + b_diff)   [per-node: E/N = 12x reuse]
    gemm_mfma<1,1,0><<<gb, blk, 0, stream>>>(x, Whi(0), Wlo(0), b_diff, nullptr, nullptr, nullptr, H, N);
    // out1 = ssp(ssp(x) @ W_same^T + b_same)
    gemm_mfma<1,1,0><<<gb, blk, 0, stream>>>(x, Whi(1), Wlo(1), b_same, nullptr, nullptr, nullptr, out1, N);
    // out1[dst] += H[src] * (ea @ Gw^T)
    edge_mfma<<<ge, blk, 0, stream>>>(ei, ea, GwB, H, out1, E);

    // residual stack
    gemm_mfma<1,0,0><<<gb, blk, 0, stream>>>(out1, Whi(2), Wlo(2), rb1,       nullptr, nullptr, nullptr, yb, N);
    gemm_mfma<1,0,1><<<gb, blk, 0, stream>>>(yb,   Whi(5), Wlo(5), rb2,       out1,    nullptr, nullptr, tb, N);
    gemm_mfma<1,0,0><<<gb, blk, 0, stream>>>(tb,   Whi(3), Wlo(3), rb1 + 128, nullptr, nullptr, nullptr, yb, N);
    gemm_mfma<1,0,1><<<gb, blk, 0, stream>>>(yb,   Whi(6), Wlo(6), rb2 + 128, tb,      nullptr, nullptr, tb, N);
    gemm_mfma<1,0,0><<<gb, blk, 0, stream>>>(tb,   Whi(4), Wlo(4), rb1 + 256, nullptr, nullptr, nullptr, yb, N);
    gemm_mfma<1,0,1><<<gb, blk, 0, stream>>>(yb,   Whi(7), Wlo(7), rb2 + 256, tb,      nullptr, nullptr, tb, N);

    // out0 = ssp(t) @ W_last^T + b_last + x*u
    gemm_mfma<1,0,2><<<gb, blk, 0, stream>>>(tb, Whi(8), Wlo(8), b_last, nullptr, x, u, out0, N);
}